// Round 2
// baseline (174.310 us; speedup 1.0000x reference)
//
#include <hip/hip_runtime.h>

#define T_FRAMES 16384
#define N_MELS 128
#define N_FREQ 513
#define REPEAT 256
#define FRAMES_PER_BLOCK 64
#define NCHUNK 8
#define BLOCK_THREADS 512
#define LOG2_10 3.3219280948873623f

__global__ __launch_bounds__(512, 2) void mel2lpc_kernel(
    const float* __restrict__ mel,   // [128][16384]
    const float* __restrict__ B,     // [513][128] inv_mel_basis
    const float* __restrict__ lag,   // [5]
    float* __restrict__ out)         // [4][16384*256]
{
  __shared__ float W_s[5][N_FREQ];
  __shared__ float red[NCHUNK][5][FRAMES_PER_BLOCK];
  __shared__ float lp_s[4][FRAMES_PER_BLOCK];

  const int tid = threadIdx.x;
  const int t0 = blockIdx.x * FRAMES_PER_BLOCK;

  // ---- Phase 0: combined cosine / lag-window / ifft-norm table ----
  // ac[k] = sum_f W[k][f] * power[f], W[k][f] = lag[k]*cf*cos(2*pi*k*f/1024)
  for (int idx = tid; idx < 5 * N_FREQ; idx += BLOCK_THREADS) {
    int k = idx / N_FREQ;
    int f = idx - k * N_FREQ;
    float cf = (f == 0 || f == N_FREQ - 1) ? (1.0f / 1024.0f) : (2.0f / 1024.0f);
    float c = cospif((float)(k * f) * (1.0f / 512.0f));
    W_s[k][f] = lag[k] * cf * c;
  }
  __syncthreads();

  const int fl = tid & 63;                                   // frame within block
  const int fc = __builtin_amdgcn_readfirstlane(tid >> 6);   // wave-uniform f-chunk
  const int t = t0 + fl;

  // ---- Phase 1: x[m] = 10^mel[m,t], kept in registers as float4[32] ----
  float4 x4[32];
#pragma unroll
  for (int i = 0; i < 32; ++i) {
    const float* mp = mel + (4 * i) * T_FRAMES + t;
    float4 v;
    v.x = exp2f(mp[0] * LOG2_10);
    v.y = exp2f(mp[1 * T_FRAMES] * LOG2_10);
    v.z = exp2f(mp[2 * T_FRAMES] * LOG2_10);
    v.w = exp2f(mp[3 * T_FRAMES] * LOG2_10);
    x4[i] = v;
  }

  // ---- Phase 2: fused matmul + clamp + square + cosine transform ----
  float acc0 = 0.f, acc1 = 0.f, acc2 = 0.f, acc3 = 0.f, acc4 = 0.f;
  const int fstart = fc * 64;
  const int fend = (fc == NCHUNK - 1) ? N_FREQ : fstart + 64;
  const float4* __restrict__ B4 = (const float4*)B;  // [513][32]

#pragma unroll 2
  for (int f = fstart; f < fend; ++f) {
    const float4* __restrict__ Br = B4 + f * 32;  // wave-uniform address
    float s0 = 0.f, s1 = 0.f, s2 = 0.f, s3 = 0.f;
#pragma unroll
    for (int i = 0; i < 32; ++i) {
      float4 b = Br[i];
      s0 = fmaf(b.x, x4[i].x, s0);
      s1 = fmaf(b.y, x4[i].y, s1);
      s2 = fmaf(b.z, x4[i].z, s2);
      s3 = fmaf(b.w, x4[i].w, s3);
    }
    float s = (s0 + s1) + (s2 + s3);
    float lin = fmaxf(s, 1e-12f);
    float p = lin * lin;
    acc0 = fmaf(W_s[0][f], p, acc0);
    acc1 = fmaf(W_s[1][f], p, acc1);
    acc2 = fmaf(W_s[2][f], p, acc2);
    acc3 = fmaf(W_s[3][f], p, acc3);
    acc4 = fmaf(W_s[4][f], p, acc4);
  }
  red[fc][0][fl] = acc0;
  red[fc][1][fl] = acc1;
  red[fc][2][fl] = acc2;
  red[fc][3][fl] = acc3;
  red[fc][4][fl] = acc4;
  __syncthreads();

  // ---- Phase 3: reduce partials + Levinson-Durbin (wave 0, 1 lane/frame) ----
  if (tid < 64) {
    float ac[5];
#pragma unroll
    for (int k = 0; k < 5; ++k) {
      float s = 0.f;
#pragma unroll
      for (int c = 0; c < NCHUNK; ++c) s += red[c][k][tid];
      ac[k] = s;
    }
    float E = ac[0];
    float k0 = ac[1] / E;
    E *= fmaxf(1.0f - k0 * k0, 1e-5f);
    float l0 = -k0;

    float a1 = ac[2] + l0 * ac[1];
    float k1 = a1 / E;
    E *= fmaxf(1.0f - k1 * k1, 1e-5f);
    float m0 = l0 - k1 * l0;
    float m1 = -k1;

    float a2 = ac[3] + m0 * ac[2] + m1 * ac[1];
    float k2 = a2 / E;
    E *= fmaxf(1.0f - k2 * k2, 1e-5f);
    float n0 = m0 - k2 * m1;
    float n1 = m1 - k2 * m0;
    float n2 = -k2;

    float a3 = ac[4] + n0 * ac[3] + n1 * ac[2] + n2 * ac[1];
    float k3 = a3 / E;
    float o0 = n0 - k3 * n2;
    float o1 = n1 - k3 * n1;
    float o2 = n2 - k3 * n0;
    float o3 = -k3;

    // lpc = [o0,o1,o2,o3]; out row j = -lpc[3-j]
    lp_s[0][tid] = -o3;
    lp_s[1][tid] = -o2;
    lp_s[2][tid] = -o1;
    lp_s[3][tid] = -o0;
  }
  __syncthreads();

  // ---- Phase 4: repeat-expand write, coalesced float4 ----
  float4* out4 = (float4*)out;
#pragma unroll
  for (int i = 0; i < 32; ++i) {
    int vid = i * BLOCK_THREADS + tid;   // 0..16383
    int j = vid >> 12;                   // output row 0..3
    int rem = vid & 4095;                // float4 index within row-chunk
    int tl = rem >> 6;                   // local frame 0..63 (wave-uniform)
    float v = lp_s[j][tl];
    float4 vv = make_float4(v, v, v, v);
    out4[(size_t)j * (T_FRAMES * REPEAT / 4) + (size_t)t0 * 64 + rem] = vv;
  }
}

extern "C" void kernel_launch(void* const* d_in, const int* in_sizes, int n_in,
                              void* d_out, int out_size, void* d_ws, size_t ws_size,
                              hipStream_t stream) {
  const float* mel = (const float*)d_in[0];
  const float* B   = (const float*)d_in[1];
  const float* lag = (const float*)d_in[2];
  float* out = (float*)d_out;
  mel2lpc_kernel<<<T_FRAMES / FRAMES_PER_BLOCK, BLOCK_THREADS, 0, stream>>>(mel, B, lag, out);
}

// Round 3
// 119.975 us; speedup vs baseline: 1.4529x; 1.4529x over previous
//
#include <hip/hip_runtime.h>

#define T_FRAMES 16384
#define N_MELS 128
#define N_FREQ 513
#define REPEAT 256
#define FPB 32             // frames per block
#define BT 512             // threads per block
#define LOG2_10 3.3219280948873623f

__global__ __launch_bounds__(BT, 4) void mel2lpc_kernel(
    const float* __restrict__ mel,   // [128][16384]
    const float* __restrict__ B,     // [513][128]
    const float* __restrict__ lag,   // [5]
    float* __restrict__ out)         // [4][16384*256]
{
  __shared__ float X_s[N_MELS][FPB];   // 16 KB: 10^mel tile
  __shared__ float W_s[5][N_FREQ];     // 10.3 KB: lag[k]*cf*cos(2pi k f/1024)
  __shared__ float red[8][5][FPB];     // 5 KB: per-wave partial ac
  __shared__ float lp_s[4][FPB];       // 0.5 KB

  const int tid = threadIdx.x;
  const int t0 = blockIdx.x * FPB;

  // ---- Phase 0a: combined cosine/lag/norm table ----
  for (int idx = tid; idx < 5 * N_FREQ; idx += BT) {
    int k = idx / N_FREQ;
    int f = idx - k * N_FREQ;
    float cf = (f == 0 || f == N_FREQ - 1) ? (1.0f / 1024.0f) : (2.0f / 1024.0f);
    W_s[k][f] = lag[k] * cf * cospif((float)(k * f) * (1.0f / 512.0f));
  }
  // ---- Phase 0b: stage X = 10^mel into LDS (coalesced) ----
#pragma unroll
  for (int r = 0; r < 8; ++r) {
    int idx = r * BT + tid;            // 0..4095
    int m = idx >> 5;
    int t = idx & 31;
    X_s[m][t] = exp2f(mel[m * T_FRAMES + t0 + t] * LOG2_10);
  }
  __syncthreads();

  const int tg = tid & 7;     // frame group: frames tg*4 .. tg*4+3
  const int fg = tid >> 3;    // 0..63: freqs fg*8 .. fg*8+7
  const int f0 = fg * 8;

  const float4* __restrict__ B4 = (const float4*)B;    // [513][32]
  const float4* __restrict__ X4 = (const float4*)X_s;  // [128][8]

  // ---- Phase 1: register-tiled GEMM, 8f x 4t per thread ----
  float4 acc[8];
#pragma unroll
  for (int ff = 0; ff < 8; ++ff) acc[ff] = make_float4(0.f, 0.f, 0.f, 0.f);

#pragma unroll 4
  for (int ms = 0; ms < 32; ++ms) {    // m = 4*ms .. 4*ms+3
    float4 x0 = X4[(4 * ms + 0) * 8 + tg];
    float4 x1 = X4[(4 * ms + 1) * 8 + tg];
    float4 x2 = X4[(4 * ms + 2) * 8 + tg];
    float4 x3 = X4[(4 * ms + 3) * 8 + tg];
#pragma unroll
    for (int ff = 0; ff < 8; ++ff) {
      float4 b = B4[(f0 + ff) * 32 + ms];
      float4 a = acc[ff];
      a.x = fmaf(b.x, x0.x, a.x); a.x = fmaf(b.y, x1.x, a.x);
      a.x = fmaf(b.z, x2.x, a.x); a.x = fmaf(b.w, x3.x, a.x);
      a.y = fmaf(b.x, x0.y, a.y); a.y = fmaf(b.y, x1.y, a.y);
      a.y = fmaf(b.z, x2.y, a.y); a.y = fmaf(b.w, x3.y, a.y);
      a.z = fmaf(b.x, x0.z, a.z); a.z = fmaf(b.y, x1.z, a.z);
      a.z = fmaf(b.z, x2.z, a.z); a.z = fmaf(b.w, x3.z, a.z);
      a.w = fmaf(b.x, x0.w, a.w); a.w = fmaf(b.y, x1.w, a.w);
      a.w = fmaf(b.z, x2.w, a.w); a.w = fmaf(b.w, x3.w, a.w);
      acc[ff] = a;
    }
  }

  // ---- Phase 2: clamp/square + cosine-weighted partial sums ----
  float pk[5][4];
#pragma unroll
  for (int k = 0; k < 5; ++k)
#pragma unroll
    for (int j = 0; j < 4; ++j) pk[k][j] = 0.f;

#pragma unroll
  for (int ff = 0; ff < 8; ++ff) {
    float w0 = W_s[0][f0 + ff], w1 = W_s[1][f0 + ff], w2 = W_s[2][f0 + ff];
    float w3 = W_s[3][f0 + ff], w4 = W_s[4][f0 + ff];
    float4 a = acc[ff];
    float lin, p;
    lin = fmaxf(a.x, 1e-12f); p = lin * lin;
    pk[0][0] = fmaf(w0, p, pk[0][0]); pk[1][0] = fmaf(w1, p, pk[1][0]);
    pk[2][0] = fmaf(w2, p, pk[2][0]); pk[3][0] = fmaf(w3, p, pk[3][0]);
    pk[4][0] = fmaf(w4, p, pk[4][0]);
    lin = fmaxf(a.y, 1e-12f); p = lin * lin;
    pk[0][1] = fmaf(w0, p, pk[0][1]); pk[1][1] = fmaf(w1, p, pk[1][1]);
    pk[2][1] = fmaf(w2, p, pk[2][1]); pk[3][1] = fmaf(w3, p, pk[3][1]);
    pk[4][1] = fmaf(w4, p, pk[4][1]);
    lin = fmaxf(a.z, 1e-12f); p = lin * lin;
    pk[0][2] = fmaf(w0, p, pk[0][2]); pk[1][2] = fmaf(w1, p, pk[1][2]);
    pk[2][2] = fmaf(w2, p, pk[2][2]); pk[3][2] = fmaf(w3, p, pk[3][2]);
    pk[4][2] = fmaf(w4, p, pk[4][2]);
    lin = fmaxf(a.w, 1e-12f); p = lin * lin;
    pk[0][3] = fmaf(w0, p, pk[0][3]); pk[1][3] = fmaf(w1, p, pk[1][3]);
    pk[2][3] = fmaf(w2, p, pk[2][3]); pk[3][3] = fmaf(w3, p, pk[3][3]);
    pk[4][3] = fmaf(w4, p, pk[4][3]);
  }

  // ---- Phase 3: reduce fg groups within wave via shfl_xor, stash per wave ----
  const int wv = tid >> 6;
  const bool writer = (tid & 63) < 8;
#pragma unroll
  for (int k = 0; k < 5; ++k) {
#pragma unroll
    for (int j = 0; j < 4; ++j) {
      float v = pk[k][j];
      v += __shfl_xor(v, 8);
      v += __shfl_xor(v, 16);
      v += __shfl_xor(v, 32);
      if (writer) red[wv][k][tg * 4 + j] = v;
    }
  }
  __syncthreads();

  // ---- Phase 4: final ac (+ f=512 row) + Levinson-Durbin, 1 lane/frame ----
  if (tid < FPB) {
    const int t = tid;
    float ac[5];
#pragma unroll
    for (int k = 0; k < 5; ++k) {
      float s = 0.f;
#pragma unroll
      for (int w = 0; w < 8; ++w) s += red[w][k][t];
      ac[k] = s;
    }
    // remainder frequency row f = 512
    float s = 0.f;
    const float* __restrict__ Bl = B + 512 * N_MELS;
#pragma unroll
    for (int m = 0; m < N_MELS; ++m) s = fmaf(Bl[m], X_s[m][t], s);
    float lin = fmaxf(s, 1e-12f);
    float p = lin * lin;
#pragma unroll
    for (int k = 0; k < 5; ++k) ac[k] = fmaf(W_s[k][512], p, ac[k]);

    float E = ac[0];
    float k0 = ac[1] / E;
    E *= fmaxf(1.0f - k0 * k0, 1e-5f);
    float l0 = -k0;

    float a1 = ac[2] + l0 * ac[1];
    float k1 = a1 / E;
    E *= fmaxf(1.0f - k1 * k1, 1e-5f);
    float m0 = l0 - k1 * l0;
    float m1 = -k1;

    float a2 = ac[3] + m0 * ac[2] + m1 * ac[1];
    float k2 = a2 / E;
    E *= fmaxf(1.0f - k2 * k2, 1e-5f);
    float n0 = m0 - k2 * m1;
    float n1 = m1 - k2 * m0;
    float n2 = -k2;

    float a3 = ac[4] + n0 * ac[3] + n1 * ac[2] + n2 * ac[1];
    float k3 = a3 / E;
    float o0 = n0 - k3 * n2;
    float o1 = n1 - k3 * n1;
    float o2 = n2 - k3 * n0;
    float o3 = -k3;

    lp_s[0][t] = -o3;
    lp_s[1][t] = -o2;
    lp_s[2][t] = -o1;
    lp_s[3][t] = -o0;
  }
  __syncthreads();

  // ---- Phase 5: repeat-expand write, coalesced float4 ----
  float4* out4 = (float4*)out;
#pragma unroll
  for (int i = 0; i < 16; ++i) {
    int vid = i * BT + tid;       // 0..8191
    int j = vid >> 11;            // output row 0..3
    int rem = vid & 2047;         // float4 idx within this block's row chunk
    int tl = rem >> 6;            // local frame 0..31
    float v = lp_s[j][tl];
    out4[(size_t)j * (T_FRAMES * REPEAT / 4) + (size_t)t0 * 64 + rem] =
        make_float4(v, v, v, v);
  }
}

extern "C" void kernel_launch(void* const* d_in, const int* in_sizes, int n_in,
                              void* d_out, int out_size, void* d_ws, size_t ws_size,
                              hipStream_t stream) {
  const float* mel = (const float*)d_in[0];
  const float* B   = (const float*)d_in[1];
  const float* lag = (const float*)d_in[2];
  float* out = (float*)d_out;
  mel2lpc_kernel<<<T_FRAMES / FPB, BT, 0, stream>>>(mel, B, lag, out);
}